// Round 5
// baseline (286.475 us; speedup 1.0000x reference)
//
#include <hip/hip_runtime.h>
#include <math.h>

#define N_NODES 10000
#define N_EDGES 320000

__device__ __forceinline__ float ssp(float x) {
    float ax = fabsf(x);
    return fmaxf(x, 0.0f) + log1pf(expf(-ax)) - 0.69314718055994531f;
}
__device__ __forceinline__ float bcastf(float v, int l) {
    return __uint_as_float(__builtin_amdgcn_readlane(__float_as_uint(v), l));
}
__device__ __forceinline__ int bcasti(int v, int l) {
    return __builtin_amdgcn_readlane(v, l);
}
__device__ __forceinline__ int div3(int q) {   // exact for 0 <= q < 32768
    return (q * 21846) >> 16;
}

// ---------------- CSR build ----------------

__global__ void count_kernel(const int* __restrict__ dst, int* __restrict__ counts, int E) {
    int e = blockIdx.x * blockDim.x + threadIdx.x;
    if (e < E) atomicAdd(&counts[dst[e]], 1);
}

__global__ __launch_bounds__(1024) void scan_kernel(const int* __restrict__ counts,
                                                    int* __restrict__ offsets,
                                                    int* __restrict__ cursor, int n) {
    __shared__ int sums[1024];
    int t = threadIdx.x;
    const int CH = (n + 1023) / 1024;
    int base = t * CH;
    int local = 0;
    for (int i = 0; i < CH; ++i) {
        int idx = base + i;
        if (idx < n) local += counts[idx];
    }
    sums[t] = local;
    __syncthreads();
    for (int off = 1; off < 1024; off <<= 1) {
        int v = sums[t];
        int add = (t >= off) ? sums[t - off] : 0;
        __syncthreads();
        sums[t] = v + add;
        __syncthreads();
    }
    int run = (t == 0) ? 0 : sums[t - 1];
    for (int i = 0; i < CH; ++i) {
        int idx = base + i;
        if (idx < n) {
            offsets[idx] = run;
            cursor[idx]  = run;
            run += counts[idx];
        }
    }
    if (t == 0) offsets[n] = sums[1023];
}

__global__ void scatter_kernel(const int* __restrict__ dst, int* __restrict__ cursor,
                               int* __restrict__ csr, int E) {
    int e = blockIdx.x * blockDim.x + threadIdx.x;
    if (e < E) {
        int d = dst[e];
        int p = atomicAdd(&cursor[d], 1);
        csr[p] = e;
    }
}

// ---------------- node pre-transform ----------------

__global__ __launch_bounds__(256) void node_pre_kernel(
        const float* __restrict__ nf0, const float* __restrict__ nf1,
        const float* __restrict__ W1_0, const float* __restrict__ W1_1,
        float* __restrict__ x0, float* __restrict__ x1T) {
    const int n = blockIdx.x;
    const int t = threadIdx.x;
    __shared__ float s_f0[64];
    __shared__ float s_f1[192];
    if (t < 64) s_f0[t] = nf0[n*64 + t];
    else        s_f1[t-64] = nf1[n*192 + (t-64)];
    __syncthreads();
    if (t < 64) {
        float acc = 0.f;
        #pragma unroll 8
        for (int u = 0; u < 64; ++u) acc += s_f0[u] * W1_0[u*64 + t];
        x0[n*64 + t] = acc * 0.125f;
    } else {
        const int c = (t - 64) >> 6;
        const int w = t & 63;
        float acc = 0.f;
        #pragma unroll 8
        for (int u = 0; u < 64; ++u) acc += s_f1[u*3 + c] * W1_1[u*64 + w];
        x1T[n*192 + c*64 + w] = acc * 0.125f;
    }
}

// ---------------- edge aggregation: one wave per node, 8-edge batches ----------------

__global__ __launch_bounds__(256) void edge_kernel(
    const float* __restrict__ eemb, const float* __restrict__ eattr,
    const int* __restrict__ esrc,
    const int* __restrict__ offsets, const int* __restrict__ csr,
    const float* __restrict__ x0g, const float* __restrict__ x1g,
    const float* __restrict__ Wr1, const float* __restrict__ Wr2,
    float* __restrict__ agg0, float* __restrict__ agg1)
{
    const int n = blockIdx.x * 4 + (threadIdx.x >> 6);
    if (n >= N_NODES) return;
    const int u = threadIdx.x & 63;
    const int j8 = u & 7;

    const float rs8 = 0.35355339059327373f;
    const float rs3 = 0.57735026918962576f;

    float wr2[4][8];
    #pragma unroll
    for (int k = 0; k < 4; ++k) {
        #pragma unroll
        for (int j = 0; j < 8; ++j) {
            float v = Wr2[j*256 + k*64 + u] * rs8;
            wr2[k][j] = (k == 3) ? v * rs3 : v;
        }
    }
    float wr1c[8];
    #pragma unroll
    for (int i = 0; i < 8; ++i) wr1c[i] = Wr1[i*8 + j8] * rs8;

    float A[8] = {0.f,0.f,0.f,0.f,0.f,0.f,0.f,0.f};

    const int start = offsets[n];
    const int cnt   = offsets[n+1] - start;

    for (int b = 0; b < cnt; b += 8) {
        const int m = cnt - b < 8 ? cnt - b : 8;
        const int slot = (u >> 3) < m ? (u >> 3) : 0;
        const int e = csr[start + b + slot];
        const int src = esrc[e];
        const float4 e0 = *reinterpret_cast<const float4*>(eemb + (size_t)e*8);
        const float4 e1 = *reinterpret_cast<const float4*>(eemb + (size_t)e*8 + 4);
        float pre = e0.x*wr1c[0] + e0.y*wr1c[1] + e0.z*wr1c[2] + e0.w*wr1c[3]
                  + e1.x*wr1c[4] + e1.y*wr1c[5] + e1.z*wr1c[6] + e1.w*wr1c[7];
        const float h  = ssp(pre);
        const float yl = eattr[(size_t)e*4 + (j8 & 3)];

        #pragma unroll
        for (int s = 0; s < 8; ++s) {
            if (s >= m) break;
            const int base = s * 8;
            const int ssrc = bcasti(src, base);
            const float* xp0 = x0g + (size_t)ssrc * 64;
            const float* xp1 = x1g + (size_t)ssrc * 192;
            const float xs0 = xp0[u];
            const float x1a = xp1[u];
            const float x1b = xp1[64 + u];
            const float x1c = xp1[128 + u];
            float w0 = 0.f, w1 = 0.f, w2 = 0.f, w3 = 0.f;
            #pragma unroll
            for (int j = 0; j < 8; ++j) {
                const float hj = bcastf(h, base + j);
                w0 += hj * wr2[0][j];
                w1 += hj * wr2[1][j];
                w2 += hj * wr2[2][j];
                w3 += hj * wr2[3][j];
            }
            const float y0 = bcastf(yl, base + 0);
            const float y1 = bcastf(yl, base + 1);
            const float y2 = bcastf(yl, base + 2);
            const float y3 = bcastf(yl, base + 3);
            A[0] += w0 * xs0 * y0;
            const float t01 = w1 * xs0;
            A[1] += t01 * y1; A[2] += t01 * y2; A[3] += t01 * y3;
            const float t10 = w2 * y0;
            A[4] += t10 * x1a; A[5] += t10 * x1b; A[6] += t10 * x1c;
            A[7] += w3 * (x1a*y1 + x1b*y2 + x1c*y3);
        }
    }

    const float rs32 = 0.17677669529663687f;
    agg0[(size_t)n*128 + u]      = A[0] * rs32;
    agg0[(size_t)n*128 + 64 + u] = A[7] * rs32;
    #pragma unroll
    for (int c = 0; c < 3; ++c) {
        agg1[(size_t)n*384 + c*128 + u]      = A[1+c] * rs32;
        agg1[(size_t)n*384 + c*128 + 64 + u] = A[4+c] * rs32;
    }
}

// ---------------- epilogue A (register-blocked GEMM): 16 nodes/block ----------------
// thread = 4 cols x 2 nodes; K=384 (128 W2_0 + 256 Wsc0)

#define SA_STRIDE 18   // 16 nodes + pad; 72B rows keep ds_read_b64 aligned
__global__ __launch_bounds__(256) void epiA_kernel(
    const float* __restrict__ nf0, const float* __restrict__ nattr,
    const float* __restrict__ agg0,
    const float* __restrict__ W2_0, const float* __restrict__ Wsc0,
    float* __restrict__ out, float* __restrict__ gbuf)
{
    __shared__ float sA[384 * SA_STRIDE];
    const int t = threadIdx.x;
    const int cg = t & 31;        // col group: cols {cg, cg+32, cg+64, cg+96}
    const int ng = t >> 5;        // node group: nodes {ng*2, ng*2+1}
    const int node0 = blockIdx.x * 16;

    // stage: i-major coalesced reads, transposed LDS write
    #pragma unroll 4
    for (int it = 0; it < 24; ++it) {
        int idx = it*256 + t;            // 0..6143 = nn*384 + i
        int q = idx >> 7;                // 0..47
        int nn = div3(q);
        int i = (q - 3*nn)*128 + (idx & 127);
        int node = node0 + nn;
        float v;
        if (i < 128) v = agg0[(size_t)node*128 + i];
        else {
            int uv = i - 128;
            v = nf0[(size_t)node*64 + (uv>>2)] * nattr[(size_t)node*4 + (uv&3)];
        }
        sA[i*SA_STRIDE + nn] = v;
    }
    __syncthreads();

    float acc1[8] = {0,0,0,0,0,0,0,0};   // [k][j]: col cg+32k, node ng*2+j
    float acc2[8] = {0,0,0,0,0,0,0,0};
    const float* sAp = &sA[ng*2];
    for (int i = 0; i < 128; ++i) {
        const float2 a = *reinterpret_cast<const float2*>(&sAp[i*SA_STRIDE]);
        #pragma unroll
        for (int k = 0; k < 4; ++k) {
            const float w = W2_0[i*128 + cg + k*32];
            acc1[k*2+0] += w * a.x;
            acc1[k*2+1] += w * a.y;
        }
    }
    const float* sAp2 = &sA[128*SA_STRIDE + ng*2];
    for (int uv = 0; uv < 256; ++uv) {
        const float2 a = *reinterpret_cast<const float2*>(&sAp2[uv*SA_STRIDE]);
        #pragma unroll
        for (int k = 0; k < 4; ++k) {
            const float w = Wsc0[uv*128 + cg + k*32];
            acc2[k*2+0] += w * a.x;
            acc2[k*2+1] += w * a.y;
        }
    }

    const float rs128 = 0.088388347648318447f;
    #pragma unroll
    for (int k = 0; k < 4; ++k) {
        const int col = cg + k*32;
        #pragma unroll
        for (int j = 0; j < 2; ++j) {
            const int node = node0 + ng*2 + j;
            const float v = ssp(acc1[k*2+j]*rs128 + acc2[k*2+j]*0.0625f);
            if (col < 64) out[(size_t)node*256 + col] = nf0[(size_t)node*64 + col] + v;
            else          gbuf[(size_t)node*64 + (col-64)] = v;
        }
    }
}

// ---------------- epilogue B (register-blocked GEMM): 32 (n,c)-rows/block ----------------
// thread = 4 cols x 2 rows; K=384 (128 W2_1 + 256 Wsc1)

#define SB_STRIDE 34   // 32 rows + pad; 136B rows keep ds_read_b64 aligned
__global__ __launch_bounds__(256) void epiB_kernel(
    const float* __restrict__ nf1, const float* __restrict__ nattr,
    const float* __restrict__ agg1,
    const float* __restrict__ W2_1, const float* __restrict__ Wsc1,
    const float* __restrict__ gbuf, float* __restrict__ out)
{
    __shared__ float sB[384 * SB_STRIDE];
    const int t = threadIdx.x;
    const int cg = t & 15;        // col group: cols {cg, cg+16, cg+32, cg+48}
    const int rg = t >> 4;        // row group: rows {rg*2, rg*2+1}
    const int row0 = blockIdx.x * 32;

    // stage: i-major coalesced reads, transposed LDS write
    #pragma unroll 4
    for (int it = 0; it < 48; ++it) {
        int idx = it*256 + t;            // 0..12287 = rr*384 + i
        int q = idx >> 7;                // 0..95
        int rr = div3(q);
        int i = (q - 3*rr)*128 + (idx & 127);
        int r = row0 + rr;
        float v = 0.f;
        if (r < 3*N_NODES) {
            int n = div3(r);
            int c = r - 3*n;
            if (i < 128) v = agg1[(size_t)n*384 + c*128 + i];
            else {
                int uv = i - 128;
                v = nf1[(size_t)n*192 + (uv>>2)*3 + c] * nattr[(size_t)n*4 + (uv&3)];
            }
        }
        sB[i*SB_STRIDE + rr] = v;
    }
    __syncthreads();

    float acc1[8] = {0,0,0,0,0,0,0,0};   // [k][j]: col cg+16k, row rg*2+j
    float acc2[8] = {0,0,0,0,0,0,0,0};
    const float* sBp = &sB[rg*2];
    for (int i = 0; i < 128; ++i) {
        const float2 a = *reinterpret_cast<const float2*>(&sBp[i*SB_STRIDE]);
        #pragma unroll
        for (int k = 0; k < 4; ++k) {
            const float w = W2_1[i*64 + cg + k*16];
            acc1[k*2+0] += w * a.x;
            acc1[k*2+1] += w * a.y;
        }
    }
    const float* sBp2 = &sB[128*SB_STRIDE + rg*2];
    for (int uv = 0; uv < 256; ++uv) {
        const float2 a = *reinterpret_cast<const float2*>(&sBp2[uv*SB_STRIDE]);
        #pragma unroll
        for (int k = 0; k < 4; ++k) {
            const float w = Wsc1[uv*64 + cg + k*16];
            acc2[k*2+0] += w * a.x;
            acc2[k*2+1] += w * a.y;
        }
    }

    const float rs128 = 0.088388347648318447f;
    #pragma unroll
    for (int j = 0; j < 2; ++j) {
        const int r = row0 + rg*2 + j;
        if (r < 3*N_NODES) {
            const int n = div3(r);
            const int c = r - 3*n;
            #pragma unroll
            for (int k = 0; k < 4; ++k) {
                const int col = cg + k*16;
                const float g = gbuf[(size_t)n*64 + col];
                const float val = acc1[k*2+j]*rs128 + acc2[k*2+j]*0.0625f;
                out[(size_t)n*256 + 64 + col*3 + c] =
                    nf1[(size_t)n*192 + col*3 + c] + val * g;
            }
        }
    }
}

// ---------------- launch ----------------

extern "C" void kernel_launch(void* const* d_in, const int* in_sizes, int n_in,
                              void* d_out, int out_size, void* d_ws, size_t ws_size,
                              hipStream_t stream) {
    const float* nf0   = (const float*)d_in[0];
    const float* nf1   = (const float*)d_in[1];
    const float* nattr = (const float*)d_in[2];
    const float* eemb  = (const float*)d_in[3];
    const float* eattr = (const float*)d_in[4];
    const int*   esrc  = (const int*)d_in[5];
    const int*   edst  = (const int*)d_in[6];
    const float* W1_0  = (const float*)d_in[7];
    const float* W1_1  = (const float*)d_in[8];
    const float* Wr1   = (const float*)d_in[9];
    const float* Wr2   = (const float*)d_in[10];
    const float* W2_0  = (const float*)d_in[11];
    const float* W2_1  = (const float*)d_in[12];
    const float* Wsc0  = (const float*)d_in[13];
    const float* Wsc1  = (const float*)d_in[14];
    float* out = (float*)d_out;

    char* ws = (char*)d_ws;
    float* x0    = (float*)ws;  ws += (size_t)N_NODES*64*sizeof(float);
    float* x1T   = (float*)ws;  ws += (size_t)N_NODES*192*sizeof(float);
    int* counts  = (int*)ws;    ws += (size_t)N_NODES*sizeof(int);
    int* offsets = (int*)ws;    ws += (size_t)(N_NODES+1)*sizeof(int);
    int* cursor  = (int*)ws;    ws += (size_t)N_NODES*sizeof(int);
    int* csr     = (int*)ws;    ws += (size_t)N_EDGES*sizeof(int);
    float* agg0  = (float*)ws;  ws += (size_t)N_NODES*128*sizeof(float);
    float* agg1  = (float*)ws;  ws += (size_t)N_NODES*384*sizeof(float);
    float* gbuf  = x0;  // alias: x0 dead after edge_kernel

    hipMemsetAsync(counts, 0, N_NODES*sizeof(int), stream);
    node_pre_kernel<<<N_NODES, 256, 0, stream>>>(nf0, nf1, W1_0, W1_1, x0, x1T);
    count_kernel<<<(N_EDGES+255)/256, 256, 0, stream>>>(edst, counts, N_EDGES);
    scan_kernel<<<1, 1024, 0, stream>>>(counts, offsets, cursor, N_NODES);
    scatter_kernel<<<(N_EDGES+255)/256, 256, 0, stream>>>(edst, cursor, csr, N_EDGES);
    edge_kernel<<<(N_NODES+3)/4, 256, 0, stream>>>(eemb, eattr, esrc, offsets, csr,
        x0, x1T, Wr1, Wr2, agg0, agg1);
    epiA_kernel<<<N_NODES/16, 256, 0, stream>>>(nf0, nattr, agg0, W2_0, Wsc0, out, gbuf);
    epiB_kernel<<<(3*N_NODES+31)/32, 256, 0, stream>>>(nf1, nattr, agg1, W2_1, Wsc1, gbuf, out);
}

// Round 6
// 264.509 us; speedup vs baseline: 1.0830x; 1.0830x over previous
//
#include <hip/hip_runtime.h>
#include <math.h>

#define N_NODES 10000
#define N_EDGES 320000

__device__ __forceinline__ float ssp(float x) {
    float ax = fabsf(x);
    return fmaxf(x, 0.0f) + log1pf(expf(-ax)) - 0.69314718055994531f;
}
__device__ __forceinline__ float bcastf(float v, int l) {
    return __uint_as_float(__builtin_amdgcn_readlane(__float_as_uint(v), l));
}
__device__ __forceinline__ int bcasti(int v, int l) {
    return __builtin_amdgcn_readlane(v, l);
}
__device__ __forceinline__ int div3(int q) {   // exact for 0 <= q < 32768
    return (q * 21846) >> 16;
}

// ---------------- CSR build ----------------

__global__ void count_kernel(const int* __restrict__ dst, int* __restrict__ counts, int E) {
    int e = blockIdx.x * blockDim.x + threadIdx.x;
    if (e < E) atomicAdd(&counts[dst[e]], 1);
}

__global__ __launch_bounds__(1024) void scan_kernel(const int* __restrict__ counts,
                                                    int* __restrict__ offsets,
                                                    int* __restrict__ cursor, int n) {
    __shared__ int sums[1024];
    int t = threadIdx.x;
    const int CH = (n + 1023) / 1024;
    int base = t * CH;
    int local = 0;
    for (int i = 0; i < CH; ++i) {
        int idx = base + i;
        if (idx < n) local += counts[idx];
    }
    sums[t] = local;
    __syncthreads();
    for (int off = 1; off < 1024; off <<= 1) {
        int v = sums[t];
        int add = (t >= off) ? sums[t - off] : 0;
        __syncthreads();
        sums[t] = v + add;
        __syncthreads();
    }
    int run = (t == 0) ? 0 : sums[t - 1];
    for (int i = 0; i < CH; ++i) {
        int idx = base + i;
        if (idx < n) {
            offsets[idx] = run;
            cursor[idx]  = run;
            run += counts[idx];
        }
    }
    if (t == 0) offsets[n] = sums[1023];
}

__global__ void scatter_kernel(const int* __restrict__ dst, int* __restrict__ cursor,
                               int* __restrict__ csr, int E) {
    int e = blockIdx.x * blockDim.x + threadIdx.x;
    if (e < E) {
        int d = dst[e];
        int p = atomicAdd(&cursor[d], 1);
        csr[p] = e;
    }
}

// ---------------- node pre-transform ----------------

__global__ __launch_bounds__(256) void node_pre_kernel(
        const float* __restrict__ nf0, const float* __restrict__ nf1,
        const float* __restrict__ W1_0, const float* __restrict__ W1_1,
        float* __restrict__ x0, float* __restrict__ x1T) {
    const int n = blockIdx.x;
    const int t = threadIdx.x;
    __shared__ float s_f0[64];
    __shared__ float s_f1[192];
    if (t < 64) s_f0[t] = nf0[n*64 + t];
    else        s_f1[t-64] = nf1[n*192 + (t-64)];
    __syncthreads();
    if (t < 64) {
        float acc = 0.f;
        #pragma unroll 8
        for (int u = 0; u < 64; ++u) acc += s_f0[u] * W1_0[u*64 + t];
        x0[n*64 + t] = acc * 0.125f;
    } else {
        const int c = (t - 64) >> 6;
        const int w = t & 63;
        float acc = 0.f;
        #pragma unroll 8
        for (int u = 0; u < 64; ++u) acc += s_f1[u*3 + c] * W1_1[u*64 + w];
        x1T[n*192 + c*64 + w] = acc * 0.125f;
    }
}

// ---------------- edge aggregation: one wave per node, 8-edge batches ----------------

__global__ __launch_bounds__(256) void edge_kernel(
    const float* __restrict__ eemb, const float* __restrict__ eattr,
    const int* __restrict__ esrc,
    const int* __restrict__ offsets, const int* __restrict__ csr,
    const float* __restrict__ x0g, const float* __restrict__ x1g,
    const float* __restrict__ Wr1, const float* __restrict__ Wr2,
    float* __restrict__ agg0, float* __restrict__ agg1)
{
    const int n = blockIdx.x * 4 + (threadIdx.x >> 6);
    if (n >= N_NODES) return;
    const int u = threadIdx.x & 63;
    const int j8 = u & 7;

    const float rs8 = 0.35355339059327373f;
    const float rs3 = 0.57735026918962576f;

    float wr2[4][8];
    #pragma unroll
    for (int k = 0; k < 4; ++k) {
        #pragma unroll
        for (int j = 0; j < 8; ++j) {
            float v = Wr2[j*256 + k*64 + u] * rs8;
            wr2[k][j] = (k == 3) ? v * rs3 : v;
        }
    }
    float wr1c[8];
    #pragma unroll
    for (int i = 0; i < 8; ++i) wr1c[i] = Wr1[i*8 + j8] * rs8;

    float A[8] = {0.f,0.f,0.f,0.f,0.f,0.f,0.f,0.f};

    const int start = offsets[n];
    const int cnt   = offsets[n+1] - start;

    for (int b = 0; b < cnt; b += 8) {
        const int m = cnt - b < 8 ? cnt - b : 8;
        const int slot = (u >> 3) < m ? (u >> 3) : 0;
        const int e = csr[start + b + slot];
        const int src = esrc[e];
        const float4 e0 = *reinterpret_cast<const float4*>(eemb + (size_t)e*8);
        const float4 e1 = *reinterpret_cast<const float4*>(eemb + (size_t)e*8 + 4);
        float pre = e0.x*wr1c[0] + e0.y*wr1c[1] + e0.z*wr1c[2] + e0.w*wr1c[3]
                  + e1.x*wr1c[4] + e1.y*wr1c[5] + e1.z*wr1c[6] + e1.w*wr1c[7];
        const float h  = ssp(pre);
        const float yl = eattr[(size_t)e*4 + (j8 & 3)];

        #pragma unroll
        for (int s = 0; s < 8; ++s) {
            if (s >= m) break;
            const int base = s * 8;
            const int ssrc = bcasti(src, base);
            const float* xp0 = x0g + (size_t)ssrc * 64;
            const float* xp1 = x1g + (size_t)ssrc * 192;
            const float xs0 = xp0[u];
            const float x1a = xp1[u];
            const float x1b = xp1[64 + u];
            const float x1c = xp1[128 + u];
            float w0 = 0.f, w1 = 0.f, w2 = 0.f, w3 = 0.f;
            #pragma unroll
            for (int j = 0; j < 8; ++j) {
                const float hj = bcastf(h, base + j);
                w0 += hj * wr2[0][j];
                w1 += hj * wr2[1][j];
                w2 += hj * wr2[2][j];
                w3 += hj * wr2[3][j];
            }
            const float y0 = bcastf(yl, base + 0);
            const float y1 = bcastf(yl, base + 1);
            const float y2 = bcastf(yl, base + 2);
            const float y3 = bcastf(yl, base + 3);
            A[0] += w0 * xs0 * y0;
            const float t01 = w1 * xs0;
            A[1] += t01 * y1; A[2] += t01 * y2; A[3] += t01 * y3;
            const float t10 = w2 * y0;
            A[4] += t10 * x1a; A[5] += t10 * x1b; A[6] += t10 * x1c;
            A[7] += w3 * (x1a*y1 + x1b*y2 + x1c*y3);
        }
    }

    const float rs32 = 0.17677669529663687f;
    agg0[(size_t)n*128 + u]      = A[0] * rs32;
    agg0[(size_t)n*128 + 64 + u] = A[7] * rs32;
    #pragma unroll
    for (int c = 0; c < 3; ++c) {
        agg1[(size_t)n*384 + c*128 + u]      = A[1+c] * rs32;
        agg1[(size_t)n*384 + c*128 + 64 + u] = A[4+c] * rs32;
    }
}

// ---------------- epilogue A: 16 nodes/block; lane=col, waves = K-half x col-half ----------------
// LDS A-tile transposed [384][16+2]; broadcast ds_read_b64 (same addr all lanes)

#define ST 18
__global__ __launch_bounds__(256) void epiA_kernel(
    const float* __restrict__ nf0, const float* __restrict__ nattr,
    const float* __restrict__ agg0,
    const float* __restrict__ W2_0, const float* __restrict__ Wsc0,
    float* __restrict__ out, float* __restrict__ gbuf)
{
    __shared__ float sA[384 * ST];        // 27648 B; partials alias first 4096 floats
    const int t = threadIdx.x;
    const int lane = t & 63;
    const int w = t >> 6;
    const int node0 = blockIdx.x * 16;

    // stage transposed: row-major global reads (coalesced in k), write [k][row]
    #pragma unroll
    for (int it = 0; it < 24; ++it) {
        int idx = it*256 + t;             // row*384 + k
        int row = div3(idx >> 7);
        int k = idx - row*384;
        int node = node0 + row;
        float v;
        if (k < 128) v = agg0[(size_t)node*128 + k];
        else {
            int uv = k - 128;
            v = nf0[(size_t)node*64 + (uv>>2)] * nattr[(size_t)node*4 + (uv&3)];
        }
        sA[k*ST + row] = v;
    }
    __syncthreads();

    float acc[16];
    #pragma unroll
    for (int r = 0; r < 16; ++r) acc[r] = 0.f;
    const int colh = w & 1, kh = w >> 1;
    const int col = colh*64 + lane;
    const float rs128 = 0.088388347648318447f;

    {   // W2_0 segment of this wave's K-half
        const int lo = kh*192, hi = lo + 192;
        const int h1 = hi < 128 ? hi : 128;
        #pragma unroll 2
        for (int kk = lo; kk < h1; ++kk) {
            const float wv = W2_0[kk*128 + col] * rs128;
            const float* ap = &sA[kk*ST];
            #pragma unroll
            for (int j = 0; j < 8; ++j) {
                float2 a = *reinterpret_cast<const float2*>(ap + 2*j);
                acc[2*j]   += wv * a.x;
                acc[2*j+1] += wv * a.y;
            }
        }
        const int l2 = lo > 128 ? lo : 128;
        #pragma unroll 2
        for (int kk = l2; kk < hi; ++kk) {
            const float wv = Wsc0[(kk-128)*128 + col] * 0.0625f;
            const float* ap = &sA[kk*ST];
            #pragma unroll
            for (int j = 0; j < 8; ++j) {
                float2 a = *reinterpret_cast<const float2*>(ap + 2*j);
                acc[2*j]   += wv * a.x;
                acc[2*j+1] += wv * a.y;
            }
        }
    }
    __syncthreads();
    // partials: [kh][row][col128]
    #pragma unroll
    for (int r = 0; r < 16; ++r) sA[kh*2048 + r*128 + col] = acc[r];
    __syncthreads();
    #pragma unroll
    for (int q = 0; q < 8; ++q) {
        int o = q*256 + t;                // row*128 + col
        float v = ssp(sA[o] + sA[2048 + o]);
        int row = o >> 7, c2 = o & 127;
        int node = node0 + row;
        if (c2 < 64) out[(size_t)node*256 + c2] = nf0[(size_t)node*64 + c2] + v;
        else         gbuf[(size_t)node*64 + (c2-64)] = v;
    }
}

// ---------------- epilogue B: 16 (n,c)-rows/block; lane=col, waves = K-quarters ----------------

__global__ __launch_bounds__(256) void epiB_kernel(
    const float* __restrict__ nf1, const float* __restrict__ nattr,
    const float* __restrict__ agg1,
    const float* __restrict__ W2_1, const float* __restrict__ Wsc1,
    const float* __restrict__ gbuf, float* __restrict__ out)
{
    __shared__ float sB[384 * ST];        // 27648 B; partials alias first 4096 floats
    const int t = threadIdx.x;
    const int lane = t & 63;
    const int w = t >> 6;
    const int row0 = blockIdx.x * 16;

    #pragma unroll
    for (int it = 0; it < 24; ++it) {
        int idx = it*256 + t;             // rr*384 + k
        int rr = div3(idx >> 7);
        int k = idx - rr*384;
        int r = row0 + rr;
        int n = div3(r);
        int c = r - 3*n;
        float v;
        if (k < 128) v = agg1[(size_t)n*384 + c*128 + k];
        else {
            int uv = k - 128;
            v = nf1[(size_t)n*192 + (uv>>2)*3 + c] * nattr[(size_t)n*4 + (uv&3)];
        }
        sB[k*ST + rr] = v;
    }
    __syncthreads();

    float acc[16];
    #pragma unroll
    for (int r = 0; r < 16; ++r) acc[r] = 0.f;
    const float rs128 = 0.088388347648318447f;
    const int lo = w*96, hi = lo + 96;
    const int h1 = hi < 128 ? hi : 128;
    #pragma unroll 2
    for (int kk = lo; kk < h1; ++kk) {
        const float wv = W2_1[kk*64 + lane] * rs128;
        const float* ap = &sB[kk*ST];
        #pragma unroll
        for (int j = 0; j < 8; ++j) {
            float2 a = *reinterpret_cast<const float2*>(ap + 2*j);
            acc[2*j]   += wv * a.x;
            acc[2*j+1] += wv * a.y;
        }
    }
    const int l2 = lo > 128 ? lo : 128;
    #pragma unroll 2
    for (int kk = l2; kk < hi; ++kk) {
        const float wv = Wsc1[(kk-128)*64 + lane] * 0.0625f;
        const float* ap = &sB[kk*ST];
        #pragma unroll
        for (int j = 0; j < 8; ++j) {
            float2 a = *reinterpret_cast<const float2*>(ap + 2*j);
            acc[2*j]   += wv * a.x;
            acc[2*j+1] += wv * a.y;
        }
    }
    __syncthreads();
    // partials: [w][row][col64]
    #pragma unroll
    for (int r = 0; r < 16; ++r) sB[w*1024 + r*64 + lane] = acc[r];
    __syncthreads();
    #pragma unroll
    for (int q = 0; q < 4; ++q) {
        int o = q*256 + t;                // row*64 + col
        float v = sB[o] + sB[1024 + o] + sB[2048 + o] + sB[3072 + o];
        int rr = o >> 6, col = o & 63;
        int r = row0 + rr;
        int n = div3(r);
        int c = r - 3*n;
        const float g = gbuf[(size_t)n*64 + col];
        out[(size_t)n*256 + 64 + col*3 + c] =
            nf1[(size_t)n*192 + col*3 + c] + v * g;
    }
}

// ---------------- launch ----------------

extern "C" void kernel_launch(void* const* d_in, const int* in_sizes, int n_in,
                              void* d_out, int out_size, void* d_ws, size_t ws_size,
                              hipStream_t stream) {
    const float* nf0   = (const float*)d_in[0];
    const float* nf1   = (const float*)d_in[1];
    const float* nattr = (const float*)d_in[2];
    const float* eemb  = (const float*)d_in[3];
    const float* eattr = (const float*)d_in[4];
    const int*   esrc  = (const int*)d_in[5];
    const int*   edst  = (const int*)d_in[6];
    const float* W1_0  = (const float*)d_in[7];
    const float* W1_1  = (const float*)d_in[8];
    const float* Wr1   = (const float*)d_in[9];
    const float* Wr2   = (const float*)d_in[10];
    const float* W2_0  = (const float*)d_in[11];
    const float* W2_1  = (const float*)d_in[12];
    const float* Wsc0  = (const float*)d_in[13];
    const float* Wsc1  = (const float*)d_in[14];
    float* out = (float*)d_out;

    char* ws = (char*)d_ws;
    float* x0    = (float*)ws;  ws += (size_t)N_NODES*64*sizeof(float);
    float* x1T   = (float*)ws;  ws += (size_t)N_NODES*192*sizeof(float);
    int* counts  = (int*)ws;    ws += (size_t)N_NODES*sizeof(int);
    int* offsets = (int*)ws;    ws += (size_t)(N_NODES+1)*sizeof(int);
    int* cursor  = (int*)ws;    ws += (size_t)N_NODES*sizeof(int);
    int* csr     = (int*)ws;    ws += (size_t)N_EDGES*sizeof(int);
    float* agg0  = (float*)ws;  ws += (size_t)N_NODES*128*sizeof(float);
    float* agg1  = (float*)ws;  ws += (size_t)N_NODES*384*sizeof(float);
    float* gbuf  = x0;  // alias: x0 dead after edge_kernel

    hipMemsetAsync(counts, 0, N_NODES*sizeof(int), stream);
    node_pre_kernel<<<N_NODES, 256, 0, stream>>>(nf0, nf1, W1_0, W1_1, x0, x1T);
    count_kernel<<<(N_EDGES+255)/256, 256, 0, stream>>>(edst, counts, N_EDGES);
    scan_kernel<<<1, 1024, 0, stream>>>(counts, offsets, cursor, N_NODES);
    scatter_kernel<<<(N_EDGES+255)/256, 256, 0, stream>>>(edst, cursor, csr, N_EDGES);
    edge_kernel<<<(N_NODES+3)/4, 256, 0, stream>>>(eemb, eattr, esrc, offsets, csr,
        x0, x1T, Wr1, Wr2, agg0, agg1);
    epiA_kernel<<<N_NODES/16, 256, 0, stream>>>(nf0, nattr, agg0, W2_0, Wsc0, out, gbuf);
    epiB_kernel<<<(3*N_NODES)/16, 256, 0, stream>>>(nf1, nattr, agg1, W2_1, Wsc1, gbuf, out);
}

// Round 7
// 251.481 us; speedup vs baseline: 1.1392x; 1.0518x over previous
//
#include <hip/hip_runtime.h>
#include <math.h>

#define N_NODES 10000
#define N_EDGES 320000

__device__ __forceinline__ float ssp(float x) {
    float ax = fabsf(x);
    return fmaxf(x, 0.0f) + log1pf(expf(-ax)) - 0.69314718055994531f;
}
__device__ __forceinline__ float bcastf(float v, int l) {
    return __uint_as_float(__builtin_amdgcn_readlane(__float_as_uint(v), l));
}
__device__ __forceinline__ int bcasti(int v, int l) {
    return __builtin_amdgcn_readlane(v, l);
}
__device__ __forceinline__ int div3(int q) {   // exact for 0 <= q < 32768
    return (q * 21846) >> 16;
}
__device__ __forceinline__ unsigned short f2bf(float f) {   // RNE
    unsigned int u = __float_as_uint(f);
    u += 0x7fff + ((u >> 16) & 1);
    return (unsigned short)(u >> 16);
}
__device__ __forceinline__ float bf2f(unsigned short h) {
    return __uint_as_float(((unsigned int)h) << 16);
}

// ---------------- CSR build ----------------

__global__ __launch_bounds__(1024) void scan_kernel(const int* __restrict__ counts,
                                                    int* __restrict__ offsets,
                                                    int* __restrict__ cursor, int n) {
    __shared__ int sums[1024];
    int t = threadIdx.x;
    const int CH = (n + 1023) / 1024;
    int base = t * CH;
    int local = 0;
    for (int i = 0; i < CH; ++i) {
        int idx = base + i;
        if (idx < n) local += counts[idx];
    }
    sums[t] = local;
    __syncthreads();
    for (int off = 1; off < 1024; off <<= 1) {
        int v = sums[t];
        int add = (t >= off) ? sums[t - off] : 0;
        __syncthreads();
        sums[t] = v + add;
        __syncthreads();
    }
    int run = (t == 0) ? 0 : sums[t - 1];
    for (int i = 0; i < CH; ++i) {
        int idx = base + i;
        if (idx < n) {
            offsets[idx] = run;
            cursor[idx]  = run;
            run += counts[idx];
        }
    }
    if (t == 0) offsets[n] = sums[1023];
}

__global__ void scatter_kernel(const int* __restrict__ dst, int* __restrict__ cursor,
                               int* __restrict__ csr, int E) {
    int e = blockIdx.x * blockDim.x + threadIdx.x;
    if (e < E) {
        int d = dst[e];
        int p = atomicAdd(&cursor[d], 1);
        csr[p] = e;
    }
}

// ---------------- node pre-transform (bf16 out) + fused edge counting ----------------

__global__ __launch_bounds__(256) void node_pre_kernel(
        const float* __restrict__ nf0, const float* __restrict__ nf1,
        const float* __restrict__ W1_0, const float* __restrict__ W1_1,
        const int* __restrict__ edst, int* __restrict__ counts,
        unsigned short* __restrict__ x0, unsigned short* __restrict__ x1T) {
    const int n = blockIdx.x;
    const int t = threadIdx.x;
    __shared__ float s_f0[64];
    __shared__ float s_f1[192];
    if (t < 64) s_f0[t] = nf0[n*64 + t];
    else        s_f1[t-64] = nf1[n*192 + (t-64)];
    // fused edge-degree count: 10000 blocks x 32 edges = 320000
    if (t >= 192 && t < 224) {
        int e = n*32 + (t - 192);
        atomicAdd(&counts[edst[e]], 1);
    }
    __syncthreads();
    if (t < 64) {
        float acc = 0.f;
        #pragma unroll 8
        for (int u = 0; u < 64; ++u) acc += s_f0[u] * W1_0[u*64 + t];
        x0[n*64 + t] = f2bf(acc * 0.125f);
    } else {
        const int c = (t - 64) >> 6;
        const int w = t & 63;
        float acc = 0.f;
        #pragma unroll 8
        for (int u = 0; u < 64; ++u) acc += s_f1[u*3 + c] * W1_1[u*64 + w];
        x1T[n*192 + c*64 + w] = f2bf(acc * 0.125f);
    }
}

// ---------------- edge aggregation: one wave per node, 8-edge batches, bf16 gathers ----------------

__global__ __launch_bounds__(256) void edge_kernel(
    const float* __restrict__ eemb, const float* __restrict__ eattr,
    const int* __restrict__ esrc,
    const int* __restrict__ offsets, const int* __restrict__ csr,
    const unsigned short* __restrict__ x0g, const unsigned short* __restrict__ x1g,
    const float* __restrict__ Wr1, const float* __restrict__ Wr2,
    float* __restrict__ agg0, float* __restrict__ agg1)
{
    const int n = blockIdx.x * 4 + (threadIdx.x >> 6);
    if (n >= N_NODES) return;
    const int u = threadIdx.x & 63;
    const int j8 = u & 7;

    const float rs8 = 0.35355339059327373f;
    const float rs3 = 0.57735026918962576f;

    float wr2[4][8];
    #pragma unroll
    for (int k = 0; k < 4; ++k) {
        #pragma unroll
        for (int j = 0; j < 8; ++j) {
            float v = Wr2[j*256 + k*64 + u] * rs8;
            wr2[k][j] = (k == 3) ? v * rs3 : v;
        }
    }
    float wr1c[8];
    #pragma unroll
    for (int i = 0; i < 8; ++i) wr1c[i] = Wr1[i*8 + j8] * rs8;

    float A[8] = {0.f,0.f,0.f,0.f,0.f,0.f,0.f,0.f};

    const int start = offsets[n];
    const int cnt   = offsets[n+1] - start;

    for (int b = 0; b < cnt; b += 8) {
        const int m = cnt - b < 8 ? cnt - b : 8;
        const int slot = (u >> 3) < m ? (u >> 3) : 0;
        const int e = csr[start + b + slot];
        const int src = esrc[e];
        const float4 e0 = *reinterpret_cast<const float4*>(eemb + (size_t)e*8);
        const float4 e1 = *reinterpret_cast<const float4*>(eemb + (size_t)e*8 + 4);
        float pre = e0.x*wr1c[0] + e0.y*wr1c[1] + e0.z*wr1c[2] + e0.w*wr1c[3]
                  + e1.x*wr1c[4] + e1.y*wr1c[5] + e1.z*wr1c[6] + e1.w*wr1c[7];
        const float h  = ssp(pre);
        const float yl = eattr[(size_t)e*4 + (j8 & 3)];

        #pragma unroll
        for (int s = 0; s < 8; ++s) {
            if (s >= m) break;
            const int base = s * 8;
            const int ssrc = bcasti(src, base);
            const unsigned short* xp0 = x0g + (size_t)ssrc * 64;
            const unsigned short* xp1 = x1g + (size_t)ssrc * 192;
            const float xs0 = bf2f(xp0[u]);
            const float x1a = bf2f(xp1[u]);
            const float x1b = bf2f(xp1[64 + u]);
            const float x1c = bf2f(xp1[128 + u]);
            float w0 = 0.f, w1 = 0.f, w2 = 0.f, w3 = 0.f;
            #pragma unroll
            for (int j = 0; j < 8; ++j) {
                const float hj = bcastf(h, base + j);
                w0 += hj * wr2[0][j];
                w1 += hj * wr2[1][j];
                w2 += hj * wr2[2][j];
                w3 += hj * wr2[3][j];
            }
            const float y0 = bcastf(yl, base + 0);
            const float y1 = bcastf(yl, base + 1);
            const float y2 = bcastf(yl, base + 2);
            const float y3 = bcastf(yl, base + 3);
            A[0] += w0 * xs0 * y0;
            const float t01 = w1 * xs0;
            A[1] += t01 * y1; A[2] += t01 * y2; A[3] += t01 * y3;
            const float t10 = w2 * y0;
            A[4] += t10 * x1a; A[5] += t10 * x1b; A[6] += t10 * x1c;
            A[7] += w3 * (x1a*y1 + x1b*y2 + x1c*y3);
        }
    }

    const float rs32 = 0.17677669529663687f;
    agg0[(size_t)n*128 + u]      = A[0] * rs32;
    agg0[(size_t)n*128 + 64 + u] = A[7] * rs32;
    #pragma unroll
    for (int c = 0; c < 3; ++c) {
        agg1[(size_t)n*384 + c*128 + u]      = A[1+c] * rs32;
        agg1[(size_t)n*384 + c*128 + 64 + u] = A[4+c] * rs32;
    }
}

// ---------------- epilogue A: 16 nodes/block; lane=col, waves = K-half x col-half ----------------

#define ST 18
__global__ __launch_bounds__(256) void epiA_kernel(
    const float* __restrict__ nf0, const float* __restrict__ nattr,
    const float* __restrict__ agg0,
    const float* __restrict__ W2_0, const float* __restrict__ Wsc0,
    float* __restrict__ out, float* __restrict__ gbuf)
{
    __shared__ float sA[384 * ST];        // 27648 B; partials alias first 4096 floats
    const int t = threadIdx.x;
    const int lane = t & 63;
    const int w = t >> 6;
    const int node0 = blockIdx.x * 16;

    #pragma unroll
    for (int it = 0; it < 24; ++it) {
        int idx = it*256 + t;             // row*384 + k
        int row = div3(idx >> 7);
        int k = idx - row*384;
        int node = node0 + row;
        float v;
        if (k < 128) v = agg0[(size_t)node*128 + k];
        else {
            int uv = k - 128;
            v = nf0[(size_t)node*64 + (uv>>2)] * nattr[(size_t)node*4 + (uv&3)];
        }
        sA[k*ST + row] = v;
    }
    __syncthreads();

    float acc[16];
    #pragma unroll
    for (int r = 0; r < 16; ++r) acc[r] = 0.f;
    const int colh = w & 1, kh = w >> 1;
    const int col = colh*64 + lane;
    const float rs128 = 0.088388347648318447f;

    {
        const int lo = kh*192, hi = lo + 192;
        const int h1 = hi < 128 ? hi : 128;
        #pragma unroll 2
        for (int kk = lo; kk < h1; ++kk) {
            const float wv = W2_0[kk*128 + col] * rs128;
            const float* ap = &sA[kk*ST];
            #pragma unroll
            for (int j = 0; j < 8; ++j) {
                float2 a = *reinterpret_cast<const float2*>(ap + 2*j);
                acc[2*j]   += wv * a.x;
                acc[2*j+1] += wv * a.y;
            }
        }
        const int l2 = lo > 128 ? lo : 128;
        #pragma unroll 2
        for (int kk = l2; kk < hi; ++kk) {
            const float wv = Wsc0[(kk-128)*128 + col] * 0.0625f;
            const float* ap = &sA[kk*ST];
            #pragma unroll
            for (int j = 0; j < 8; ++j) {
                float2 a = *reinterpret_cast<const float2*>(ap + 2*j);
                acc[2*j]   += wv * a.x;
                acc[2*j+1] += wv * a.y;
            }
        }
    }
    __syncthreads();
    #pragma unroll
    for (int r = 0; r < 16; ++r) sA[kh*2048 + r*128 + col] = acc[r];
    __syncthreads();
    #pragma unroll
    for (int q = 0; q < 8; ++q) {
        int o = q*256 + t;                // row*128 + col
        float v = ssp(sA[o] + sA[2048 + o]);
        int row = o >> 7, c2 = o & 127;
        int node = node0 + row;
        if (c2 < 64) out[(size_t)node*256 + c2] = nf0[(size_t)node*64 + c2] + v;
        else         gbuf[(size_t)node*64 + (c2-64)] = v;
    }
}

// ---------------- epilogue B: 16 (n,c)-rows/block; lane=col, waves = K-quarters ----------------

__global__ __launch_bounds__(256) void epiB_kernel(
    const float* __restrict__ nf1, const float* __restrict__ nattr,
    const float* __restrict__ agg1,
    const float* __restrict__ W2_1, const float* __restrict__ Wsc1,
    const float* __restrict__ gbuf, float* __restrict__ out)
{
    __shared__ float sB[384 * ST];
    const int t = threadIdx.x;
    const int lane = t & 63;
    const int w = t >> 6;
    const int row0 = blockIdx.x * 16;

    #pragma unroll
    for (int it = 0; it < 24; ++it) {
        int idx = it*256 + t;             // rr*384 + k
        int rr = div3(idx >> 7);
        int k = idx - rr*384;
        int r = row0 + rr;
        int n = div3(r);
        int c = r - 3*n;
        float v;
        if (k < 128) v = agg1[(size_t)n*384 + c*128 + k];
        else {
            int uv = k - 128;
            v = nf1[(size_t)n*192 + (uv>>2)*3 + c] * nattr[(size_t)n*4 + (uv&3)];
        }
        sB[k*ST + rr] = v;
    }
    __syncthreads();

    float acc[16];
    #pragma unroll
    for (int r = 0; r < 16; ++r) acc[r] = 0.f;
    const float rs128 = 0.088388347648318447f;
    const int lo = w*96, hi = lo + 96;
    const int h1 = hi < 128 ? hi : 128;
    #pragma unroll 2
    for (int kk = lo; kk < h1; ++kk) {
        const float wv = W2_1[kk*64 + lane] * rs128;
        const float* ap = &sB[kk*ST];
        #pragma unroll
        for (int j = 0; j < 8; ++j) {
            float2 a = *reinterpret_cast<const float2*>(ap + 2*j);
            acc[2*j]   += wv * a.x;
            acc[2*j+1] += wv * a.y;
        }
    }
    const int l2 = lo > 128 ? lo : 128;
    #pragma unroll 2
    for (int kk = l2; kk < hi; ++kk) {
        const float wv = Wsc1[(kk-128)*64 + lane] * 0.0625f;
        const float* ap = &sB[kk*ST];
        #pragma unroll
        for (int j = 0; j < 8; ++j) {
            float2 a = *reinterpret_cast<const float2*>(ap + 2*j);
            acc[2*j]   += wv * a.x;
            acc[2*j+1] += wv * a.y;
        }
    }
    __syncthreads();
    #pragma unroll
    for (int r = 0; r < 16; ++r) sB[w*1024 + r*64 + lane] = acc[r];
    __syncthreads();
    #pragma unroll
    for (int q = 0; q < 4; ++q) {
        int o = q*256 + t;                // row*64 + col
        float v = sB[o] + sB[1024 + o] + sB[2048 + o] + sB[3072 + o];
        int rr = o >> 6, col = o & 63;
        int r = row0 + rr;
        int n = div3(r);
        int c = r - 3*n;
        const float g = gbuf[(size_t)n*64 + col];
        out[(size_t)n*256 + 64 + col*3 + c] =
            nf1[(size_t)n*192 + col*3 + c] + v * g;
    }
}

// ---------------- launch ----------------

extern "C" void kernel_launch(void* const* d_in, const int* in_sizes, int n_in,
                              void* d_out, int out_size, void* d_ws, size_t ws_size,
                              hipStream_t stream) {
    const float* nf0   = (const float*)d_in[0];
    const float* nf1   = (const float*)d_in[1];
    const float* nattr = (const float*)d_in[2];
    const float* eemb  = (const float*)d_in[3];
    const float* eattr = (const float*)d_in[4];
    const int*   esrc  = (const int*)d_in[5];
    const int*   edst  = (const int*)d_in[6];
    const float* W1_0  = (const float*)d_in[7];
    const float* W1_1  = (const float*)d_in[8];
    const float* Wr1   = (const float*)d_in[9];
    const float* Wr2   = (const float*)d_in[10];
    const float* W2_0  = (const float*)d_in[11];
    const float* W2_1  = (const float*)d_in[12];
    const float* Wsc0  = (const float*)d_in[13];
    const float* Wsc1  = (const float*)d_in[14];
    float* out = (float*)d_out;

    char* ws = (char*)d_ws;
    unsigned short* x0  = (unsigned short*)ws;  ws += (size_t)N_NODES*64*sizeof(unsigned short);
    unsigned short* x1T = (unsigned short*)ws;  ws += (size_t)N_NODES*192*sizeof(unsigned short);
    int* counts  = (int*)ws;    ws += (size_t)N_NODES*sizeof(int);
    int* offsets = (int*)ws;    ws += (size_t)(N_NODES+1)*sizeof(int);
    int* cursor  = (int*)ws;    ws += (size_t)N_NODES*sizeof(int);
    int* csr     = (int*)ws;    ws += (size_t)N_EDGES*sizeof(int);
    float* agg0  = (float*)ws;  ws += (size_t)N_NODES*128*sizeof(float);
    float* agg1  = (float*)ws;  ws += (size_t)N_NODES*384*sizeof(float);
    float* gbuf  = (float*)ws;  ws += (size_t)N_NODES*64*sizeof(float);

    hipMemsetAsync(counts, 0, N_NODES*sizeof(int), stream);
    node_pre_kernel<<<N_NODES, 256, 0, stream>>>(nf0, nf1, W1_0, W1_1, edst, counts, x0, x1T);
    scan_kernel<<<1, 1024, 0, stream>>>(counts, offsets, cursor, N_NODES);
    scatter_kernel<<<(N_EDGES+255)/256, 256, 0, stream>>>(edst, cursor, csr, N_EDGES);
    edge_kernel<<<(N_NODES+3)/4, 256, 0, stream>>>(eemb, eattr, esrc, offsets, csr,
        x0, x1T, Wr1, Wr2, agg0, agg1);
    epiA_kernel<<<N_NODES/16, 256, 0, stream>>>(nf0, nattr, agg0, W2_0, Wsc0, out, gbuf);
    epiB_kernel<<<(3*N_NODES)/16, 256, 0, stream>>>(nf1, nattr, agg1, W2_1, Wsc1, gbuf, out);
}